// Round 11
// baseline (4652.210 us; speedup 1.0000x reference)
//
#include <hip/hip_runtime.h>
#include <math.h>
#include <stddef.h>

// ---------------------------------------------------------------------------
// ATT_SYN: bi-LSTM encoder + synopsis attention + 2nd bi-LSTM + tag head.
// B=8 T=512 S=32 J=64 D=400 R=256 MDU=100 TAGS=7
// Recurrence: cooperative 2-WG-per-direction kernel, 512 threads (8 waves)
// per WG; each wave owns one 64x256 bf16 Whh slice in 128 VGPRs (per-wave
// MFMA work identical to the 4-WG round-9 kernel — round 1's 2-WG failure
// doubled per-wave work; this halves exchange parties WITHOUT that).
// Per-step sync: round-9-verified machinery exactly (per-WG flag on own
// 64B line, release store after drain+barrier, tid0 relaxed poll of the 2
// member flags + acquire fence + barrier). Round-10's tagged exchange is
// REVERTED (poll bandwidth scaled with data volume -> read storm, +15%).
// Host-side: fused prep_k / castAB_k / cast3_k, fast phase-C activations.
// ---------------------------------------------------------------------------

#define BB 8
#define TT 512
#define SS 32
#define JJ 64
#define DD 400
#define RR 256
#define G4 1024
#define H2 512
#define MDU_ 100
#define TAGS_ 7
#define BT (BB*TT)
#define NSEQ (BB*SS)
#define SCH 64
#define MB1 (1024*1024)

typedef __attribute__((ext_vector_type(8))) short short8;
typedef __attribute__((ext_vector_type(4))) float floatx4;
typedef __attribute__((ext_vector_type(4))) unsigned int u32x4;
typedef unsigned short u16;
typedef unsigned int u32;

struct Ptr6 { const void* p[6]; };

__device__ __forceinline__ float us2f(u16 u) {
    unsigned int v = ((unsigned int)u) << 16;
    return __builtin_bit_cast(float, v);
}
__device__ __forceinline__ u16 f2us(float f) {
    unsigned int v = __builtin_bit_cast(unsigned int, f);
    v += 0x7FFFu + ((v >> 16) & 1u);
    return (u16)(v >> 16);
}
__device__ __forceinline__ float ldin(const void* p, long i, int bf) {
    return bf ? us2f(((const u16*)p)[i]) : ((const float*)p)[i];
}
// fast activations (NaN-safe; recurrence path since round 2)
__device__ __forceinline__ float sigm_f(float x) { return 1.0f / (1.0f + __expf(-x)); }
__device__ __forceinline__ float tanh_f(float x) {
    float e = __expf(-2.0f * fabsf(x));
    float t = (1.0f - e) / (1.0f + e);
    return copysignf(t, x);
}

// ---- dtype probe ----
__global__ void detect_k(const void* x, int* flag) {
    __shared__ int cnt;
    if (threadIdx.x == 0) cnt = 0;
    __syncthreads();
    u16 lo = ((const u16*)x)[threadIdx.x * 2];
    int e = (lo >> 7) & 0xFF;
    if (e >= 118 && e <= 131) atomicAdd(&cnt, 1);
    __syncthreads();
    if (threadIdx.x == 0) *flag = (cnt > 128) ? 1 : 0;
}
__global__ void castbf_k(const void* src, long off, u16* dst, long n, const int* flag) {
    long i = (long)blockIdx.x * 256 + threadIdx.x;
    if (i < n) dst[i] = (*flag) ? ((const u16*)src)[off + i] : f2us(((const float*)src)[off + i]);
}

// ---- fused prep: all weight transforms + counter zeroing, one launch ----
__global__ void prep_k(const int* __restrict__ flag,
    const void* Wcwh, const void* Wcwu, const void* Wws, const void* Wout,
    const void* Wv, const void* bout, const void* WsWh, const void* WsWu,
    u16* Wcwh16, u16* Wcwu16, u16* Wws16, u16* Wout16,
    float* WvF, float* boutF, u16* WsumB, float* bsumAll,
    Ptr6 bih, Ptr6 bhh, Ptr6 whh, u16* WFall, u32* cnts)
{
    const int bf = *flag;
    long i = (long)blockIdx.x * 256 + threadIdx.x;
    if (i < 51200) { Wcwh16[i] = f2us(ldin(Wcwh, i, bf)); return; }
    i -= 51200;
    if (i < 51200) { Wcwu16[i] = f2us(ldin(Wcwu, i, bf)); return; }
    i -= 51200;
    if (i < 51200) { Wws16[i] = f2us(ldin(Wws, i, bf)); return; }
    i -= 51200;
    if (i < 10752) { Wout16[i] = f2us(ldin(Wout, i, bf)); return; }
    i -= 10752;
    if (i < 100) { WvF[i] = ldin(Wv, i, bf); return; }
    i -= 100;
    if (i < 7) { boutF[i] = ldin(bout, i, bf); return; }
    i -= 7;
    if (i < 6 * 1024) {
        int l = (int)(i >> 10), k = (int)(i & 1023);
        bsumAll[l * 1024 + k] = ldin(bih.p[l], k, bf) + ldin(bhh.p[l], k, bf);
        return;
    }
    i -= 6 * 1024;
    if (i < 262144) { WsumB[i] = f2us(ldin(WsWh, i, bf) + ldin(WsWu, i, bf)); return; }
    i -= 262144;
    if (i < 6L * 262144) {
        // Whh [1024,256] -> pre-swizzled MFMA B-fragments (4-slice partition):
        // ii = ((((s*4+w)*4+t)*8+c)*64+ln)*8+j
        int l  = (int)(i >> 18);
        int ii = (int)(i & 262143);
        int j  = ii & 7;
        int ln = (ii >> 3) & 63;
        int c  = (ii >> 9) & 7;
        int t  = (ii >> 12) & 3;
        int w  = (ii >> 14) & 3;
        int s  = (ii >> 16) & 3;
        int n_g = w * 256 + s * 64 + t * 16 + (ln & 15);
        int k   = c * 32 + (ln >> 4) * 8 + j;
        WFall[(size_t)l * 262144 + ii] = f2us(ldin(whh.p[l], (long)n_g * 256 + k, bf));
        return;
    }
    i -= 6L * 262144;
    if (i < 8192) cnts[i] = 0u;
}

// ---- fused A+B input casts (bigws path), one launch ----
__global__ void castAB_k(const void* xsyn, u16* mx16,
                         const void* wih2, u16* mW16a,
                         const void* wih3, u16* mW16b,
                         const void* xtext, u16* x16c,
                         const void* wih0, u16* W16ac,
                         const void* wih1, u16* W16bc,
                         const int* __restrict__ flag)
{
    const int bf = *flag;
    long i = (long)blockIdx.x * 256 + threadIdx.x;
    const long nsyn = (long)NSEQ * JJ * DD;
    const long nw   = (long)G4 * DD;
    const long ntxt = (long)BT * DD;
    if (i < nsyn) { mx16[i] = f2us(ldin(xsyn, i, bf)); return; }
    i -= nsyn;
    if (i < nw) { mW16a[i] = f2us(ldin(wih2, i, bf)); return; }
    i -= nw;
    if (i < nw) { mW16b[i] = f2us(ldin(wih3, i, bf)); return; }
    i -= nw;
    if (i < ntxt) { x16c[i] = f2us(ldin(xtext, i, bf)); return; }
    i -= ntxt;
    if (i < nw) { W16ac[i] = f2us(ldin(wih0, i, bf)); return; }
    i -= nw;
    if (i < nw) { W16bc[i] = f2us(ldin(wih1, i, bf)); return; }
}

// ---- generic fused 3-segment cast ----
__global__ void cast3_k(const void* s0, u16* d0, long n0,
                        const void* s1, u16* d1, long n1,
                        const void* s2, u16* d2, long n2,
                        const int* __restrict__ flag)
{
    const int bf = *flag;
    long i = (long)blockIdx.x * 256 + threadIdx.x;
    if (i < n0) { d0[i] = f2us(ldin(s0, i, bf)); return; }
    i -= n0;
    if (i < n1) { d1[i] = f2us(ldin(s1, i, bf)); return; }
    i -= n1;
    if (i < n2) { d2[i] = f2us(ldin(s2, i, bf)); return; }
}

// ---------------------------------------------------------------------------
// GEMM: C[M,N] = A[M,K] @ W[N,K]^T (+bias); A,W bf16; C f32 or bf16.
// ---------------------------------------------------------------------------
#define BM 128
#define BN 128
#define BK 32
#define LDT 40

__global__ __launch_bounds__(256)
void gemm_bt(const u16* __restrict__ A, int lda,
             const u16* __restrict__ W, int ldw,
             void* __restrict__ C, int ldc,
             const float* __restrict__ bias,
             int M, int N, int K, int outBf16)
{
    __shared__ alignas(16) short As[BM * LDT];
    __shared__ alignas(16) short Bs[BN * LDT];
    const int tid  = threadIdx.x;
    const int m0   = blockIdx.y * BM;
    const int n0   = blockIdx.x * BN;
    const int lane = tid & 63;
    const int wave = tid >> 6;
    const int wm   = wave >> 1, wn = wave & 1;
    const int quad = lane >> 4, mrow = lane & 15;

    floatx4 acc[4][4];
#pragma unroll
    for (int i = 0; i < 4; ++i)
#pragma unroll
        for (int j = 0; j < 4; ++j) { floatx4 z4 = {0.f,0.f,0.f,0.f}; acc[i][j] = z4; }

    for (int k0 = 0; k0 < K; k0 += BK) {
#pragma unroll
        for (int cc = 0; cc < 2; ++cc) {
            int c   = tid + cc * 256;
            int row = c >> 2;
            int kc  = (c & 3) << 3;
            int gk  = k0 + kc;
            {
                int gr = m0 + row;
                short8 v;
                if (gr < M && gk + 8 <= K) {
                    v = *(const short8*)(A + (size_t)gr * lda + gk);
                } else {
#pragma unroll
                    for (int e = 0; e < 8; ++e)
                        v[e] = (gr < M && (gk + e) < K) ? (short)A[(size_t)gr * lda + gk + e] : (short)0;
                }
                *(short8*)&As[row * LDT + kc] = v;
            }
            {
                int gn = n0 + row;
                short8 v;
                if (gn < N && gk + 8 <= K) {
                    v = *(const short8*)(W + (size_t)gn * ldw + gk);
                } else {
#pragma unroll
                    for (int e = 0; e < 8; ++e)
                        v[e] = (gn < N && (gk + e) < K) ? (short)W[(size_t)gn * ldw + gk + e] : (short)0;
                }
                *(short8*)&Bs[row * LDT + kc] = v;
            }
        }
        __syncthreads();

        short8 af[4], bf[4];
#pragma unroll
        for (int i = 0; i < 4; ++i)
            af[i] = *(const short8*)&As[(wm * 64 + i * 16 + mrow) * LDT + quad * 8];
#pragma unroll
        for (int j = 0; j < 4; ++j)
            bf[j] = *(const short8*)&Bs[(wn * 64 + j * 16 + mrow) * LDT + quad * 8];
#pragma unroll
        for (int i = 0; i < 4; ++i)
#pragma unroll
            for (int j = 0; j < 4; ++j)
                acc[i][j] = __builtin_amdgcn_mfma_f32_16x16x32_bf16(af[i], bf[j], acc[i][j], 0, 0, 0);
        __syncthreads();
    }

#pragma unroll
    for (int i = 0; i < 4; ++i)
#pragma unroll
        for (int j = 0; j < 4; ++j)
#pragma unroll
            for (int r = 0; r < 4; ++r) {
                int row = m0 + wm * 64 + i * 16 + quad * 4 + r;
                int col = n0 + wn * 64 + j * 16 + mrow;
                if (row < M && col < N) {
                    float v = acc[i][j][r];
                    if (bias) v += bias[col];
                    if (outBf16) ((u16*)C)[(size_t)row * ldc + col] = f2us(v);
                    else         ((float*)C)[(size_t)row * ldc + col] = v;
                }
            }
}

// ---------------------------------------------------------------------------
// Cooperative LSTM, 2 WGs x 512 threads per (dir,batch) group. Flat grid of
// 2*G8 WGs: member p = wgid/G8 (col half p*128..p*128+127), g = wgid%G8
// (group = dir*nb+bat, active if g < 2*nb). G8 % 8 == 0 so both members
// share wgid mod 8 -> same XCD under round-robin dispatch (heuristic only).
// Each WG: 8 waves; wave w -> (gate wv = w&3, sub-slice sub = w>>2); each
// wave's 64x256 bf16 Whh slice resident in 128 VGPRs (per-wave MFMA work
// IDENTICAL to the 4-WG kernel). M=8 seqs/group. Per-step sync = round-9
// machinery: per-WG flag on own 64B line (release after drain+barrier),
// tid0 relaxed poll of both member flags + acquire fence + barrier.
// Deferred output stores + x prefetch overlap the spin. c-state in regs.
// launch_bounds(512,2) caps VGPR at 256 (need ~200) -> 8-wave WG launches.
// ---------------------------------------------------------------------------
__global__ __launch_bounds__(512, 2)
void lstm_coop(const u16* __restrict__ xWf, const u16* __restrict__ xWb,
               const u16* __restrict__ WFf, const u16* __restrict__ WFb,
               int L,
               u16* __restrict__ hOut, int hStride,
               u16* __restrict__ cOut, int cStride,
               const int* __restrict__ lenp,
               int writeAtSource, int lastOnly, int seqBase,
               u32* __restrict__ hx32, u32* __restrict__ flags,
               int grpBase, int nb, int G8)
{
    const int wgid = blockIdx.x;
    const int p    = wgid / G8;          // member: col half p*128..
    const int g    = wgid - p * G8;      // group id
    if (g >= 2 * nb) return;
    const int dir  = g / nb;
    const int bat  = g - dir * nb;
    const int tid = threadIdx.x;
    const int wv  = (tid >> 6) & 3;      // gate type i,f,g,o
    const int sub = tid >> 8;            // sub-slice 0/1 within the half
    const int ln  = tid & 63;
    const int q   = ln >> 4, m = ln & 15;
    const u16* xW = dir ? xWb : xWf;
    const u16* WF = dir ? WFb : WFf;
    const int grp = grpBase + g;
    u32* flg = flags + (size_t)grp * 64;    // 2 slots, one 64B line each
    u32* hx  = hx32 + (size_t)grp * 2048;   // [2 parity][8 seq][128 u32]

    __shared__ float g_s[4 * 8 * 128];      // [gate][seq][128 local cols]

    // resident B fragments: slice index sGlob = p*2+sub; 4 N-tiles x 8 K-chunks
    short8 bw[4][8];
    {
        const int sGlob = p * 2 + sub;
        const u16* wb = WF + ((size_t)(sGlob * 4 + wv) * 32) * 512 + ln * 8;
#pragma unroll
        for (int t4 = 0; t4 < 4; ++t4)
#pragma unroll
            for (int c = 0; c < 8; ++c)
                bw[t4][c] = *(const short8*)(wb + (size_t)(t4 * 8 + c) * 512);
    }

    const int seqU = tid >> 6;             // update phase: seq 0..7 (one wave each)
    const int j0   = (tid & 63) * 2;       // local col pair within the 128-half
    const int gcol = p * 128 + j0;         // global gate col in [0,256)
    const int mylen = lenp ? lenp[bat * 8 + seqU] : 0x7fffffff;
    float cR0 = 0.f, cR1 = 0.f;            // c-state: exclusively this thread's

    // preload x gate values for t=0
    u32 px0, px1, px2, px3;
    {
        const int tt0 = dir ? (L - 1) : 0;
        const u16* xr = xW + (((size_t)(bat * 8 + seqU)) * L + tt0) * G4 + gcol;
        px0 = *(const u32*)xr;
        px1 = *(const u32*)(xr + 256);
        px2 = *(const u32*)(xr + 512);
        px3 = *(const u32*)(xr + 768);
    }

    for (int t = 0; t < L; ++t) {
        const int tt = dir ? (L - 1 - t) : t;
        // ---- A fragments from hx[(t-1)&1] (full 256-col h, 8 seqs)
        short8 a[8];
        if (t > 0) {
            const u32* hp = hx + ((t - 1) & 1) * 1024 + m * 128;
#pragma unroll
            for (int c = 0; c < 8; ++c) {
                if (m < 8) {
                    u32x4 v = *(const u32x4*)(hp + c * 16 + q * 4);
                    a[c] = __builtin_bit_cast(short8, v);
                } else {
                    short8 z = {0,0,0,0,0,0,0,0}; a[c] = z;
                }
            }
        } else {
            short8 z = {0,0,0,0,0,0,0,0};
#pragma unroll
            for (int c = 0; c < 8; ++c) a[c] = z;
        }
        floatx4 acc[4];
#pragma unroll
        for (int t4 = 0; t4 < 4; ++t4) { floatx4 z4 = {0.f,0.f,0.f,0.f}; acc[t4] = z4; }
#pragma unroll
        for (int c = 0; c < 8; ++c)
#pragma unroll
            for (int t4 = 0; t4 < 4; ++t4)
                acc[t4] = __builtin_amdgcn_mfma_f32_16x16x32_bf16(a[c], bw[t4][c], acc[t4], 0, 0, 0);
        // C layout: seq = q*4+r (valid q<2), local col = sub*64 + t4*16 + m
        if (q < 2) {
#pragma unroll
            for (int t4 = 0; t4 < 4; ++t4)
#pragma unroll
                for (int r = 0; r < 4; ++r)
                    g_s[(wv * 8 + q * 4 + r) * 128 + sub * 64 + t4 * 16 + m] = acc[t4][r];
        }
        __syncthreads();
        // ---- gate fuse + state update: thread -> (seqU, local cols j0..j0+1)
        float hn0, hn1, cn0, cn1;
        {
            float i0 = g_s[(0 * 8 + seqU) * 128 + j0]     + us2f((u16)(px0 & 0xffffu));
            float i1 = g_s[(0 * 8 + seqU) * 128 + j0 + 1] + us2f((u16)(px0 >> 16));
            float f0 = g_s[(1 * 8 + seqU) * 128 + j0]     + us2f((u16)(px1 & 0xffffu));
            float f1 = g_s[(1 * 8 + seqU) * 128 + j0 + 1] + us2f((u16)(px1 >> 16));
            float g0 = g_s[(2 * 8 + seqU) * 128 + j0]     + us2f((u16)(px2 & 0xffffu));
            float g1 = g_s[(2 * 8 + seqU) * 128 + j0 + 1] + us2f((u16)(px2 >> 16));
            float o0 = g_s[(3 * 8 + seqU) * 128 + j0]     + us2f((u16)(px3 & 0xffffu));
            float o1 = g_s[(3 * 8 + seqU) * 128 + j0 + 1] + us2f((u16)(px3 >> 16));
            cn0 = sigm_f(f0) * cR0 + sigm_f(i0) * tanh_f(g0);
            cn1 = sigm_f(f1) * cR1 + sigm_f(i1) * tanh_f(g1);
            hn0 = sigm_f(o0) * tanh_f(cn0);
            hn1 = sigm_f(o1) * tanh_f(cn1);
            cR0 = cn0;
            cR1 = cn1;
            u32 hpack = (u32)f2us(hn0) | ((u32)f2us(hn1) << 16);
            __hip_atomic_store(hx + (t & 1) * 1024 + seqU * 128 + (gcol >> 1),
                               hpack, __ATOMIC_RELAXED, __HIP_MEMORY_SCOPE_AGENT);
        }
        // drain own agent-scope hx store, then barrier, then signal
        asm volatile("s_waitcnt vmcnt(0)" ::: "memory");
        __syncthreads();
        const bool last = (t == L - 1);
        if (tid == 0 && !last)
            __hip_atomic_store(&flg[p * 16], (u32)(t + 1),
                               __ATOMIC_RELEASE, __HIP_MEMORY_SCOPE_AGENT);
        // ---- deferred global outputs: overlap the spin (also flushes flag)
        if (!lastOnly) {
            int wr = writeAtSource ? tt : t;
            float mk = (wr >= mylen) ? 0.f : 1.f;
            size_t ro = ((size_t)(bat * 8 + seqU)) * L + wr;
            u32 hp2 = (u32)f2us(hn0 * mk) | ((u32)f2us(hn1 * mk) << 16);
            *(u32*)(hOut + ro * hStride + dir * RR + gcol) = hp2;
            if (cOut) {
                u32 cp2 = (u32)f2us(cn0 * mk) | ((u32)f2us(cn1 * mk) << 16);
                *(u32*)(cOut + ro * cStride + dir * RR + gcol) = cp2;
            }
        } else if (last) {
            size_t ro = (size_t)(seqBase + bat * 8 + seqU);
            u32 hp2 = (u32)f2us(hn0) | ((u32)f2us(hn1) << 16);
            *(u32*)(hOut + ro * hStride + dir * RR + gcol) = hp2;
        }
        if (!last) {
            // prefetch next-step x gate values (in flight during the spin)
            {
                const int tn = dir ? (L - 2 - t) : (t + 1);
                const u16* xr = xW + (((size_t)(bat * 8 + seqU)) * L + tn) * G4 + gcol;
                px0 = *(const u32*)xr;
                px1 = *(const u32*)(xr + 256);
                px2 = *(const u32*)(xr + 512);
                px3 = *(const u32*)(xr + 768);
            }
            // tid0-only relaxed poll of the 2 member flags; acquire fence on
            // exit invalidates this CU's L1 so hx reloads fetch fresh lines.
            if (tid == 0) {
                const u32 tgt = (u32)(t + 1);
                long guard = 0;
                for (;;) {
                    u32 f0 = __hip_atomic_load(&flg[0],  __ATOMIC_RELAXED, __HIP_MEMORY_SCOPE_AGENT);
                    u32 f1 = __hip_atomic_load(&flg[16], __ATOMIC_RELAXED, __HIP_MEMORY_SCOPE_AGENT);
                    if (f0 >= tgt && f1 >= tgt) break;
                    if (++guard > (1L << 18)) break;   // diagnostic bail
                    if (guard > 32) __builtin_amdgcn_s_sleep(1);
                }
                __builtin_amdgcn_fence(__ATOMIC_ACQUIRE, "agent");
            }
            __syncthreads();
        }
    }
}

// ------------------------- small fused kernels -----------------------------
__global__ void hprev_k(const u16* __restrict__ G, u16* __restrict__ Hp) {
    int idx = blockIdx.x * 256 + threadIdx.x;
    if (idx < BT * H2) {
        int r = idx >> 9, d = idx & 511;
        int t = r & (TT - 1);
        Hp[idx] = (t == 0) ? (u16)0 : G[(size_t)(r - 1) * G4 + d];
    }
}
__global__ void s_k(const float* __restrict__ e, const u16* __restrict__ mB,
                    u16* __restrict__ sB) {
    int i = blockIdx.x * 256 + threadIdx.x;
    if (i < BT * H2) sB[i] = f2us(sigm_f(e[i]) * tanh_f(us2f(mB[i])));
}
__global__ void z_k(const float* __restrict__ cWh, const float* __restrict__ cWu,
                    const float* __restrict__ Wv, float* __restrict__ z) {
    int idx = blockIdx.x * 256 + threadIdx.x;
    if (idx >= BT * SS) return;
    int r = idx >> 5, s = idx & 31;
    int b = r >> 9;
    const float* ph = cWh + (size_t)r * MDU_;
    const float* pu = cWu + (size_t)(b * SS + s) * MDU_;
    float acc = 0.f;
#pragma unroll 4
    for (int j = 0; j < MDU_; ++j) acc += tanh_f(ph[j] + pu[j]) * Wv[j];
    z[idx] = acc;
}
__global__ void zhat_k(const float* __restrict__ sW, const float* __restrict__ cWh,
                       const float* __restrict__ Wv, float* __restrict__ zhat) {
    int r = blockIdx.x * 256 + threadIdx.x;
    if (r >= BT) return;
    float acc = 0.f;
    const float* ps = sW + (size_t)r * MDU_;
    const float* ph = cWh + (size_t)r * MDU_;
#pragma unroll 4
    for (int j = 0; j < MDU_; ++j) acc += tanh_f(ps[j] + ph[j]) * Wv[j];
    zhat[r] = acc;
}
__global__ __launch_bounds__(64)
void attn_mix_k(const float* __restrict__ z, const float* __restrict__ zhat,
                const u16* __restrict__ U, const u16* __restrict__ sB,
                u16* __restrict__ G) {
    int r = blockIdx.x;
    int lane = threadIdx.x;
    int b = r >> 9;
    __shared__ float alpha[SS];
    float zv = (lane < SS) ? z[(size_t)r * SS + lane] : -1e30f;
    float mx = zv;
    for (int o = 32; o > 0; o >>= 1) mx = fmaxf(mx, __shfl_xor(mx, o));
    float ez = (lane < SS) ? expf(zv - mx) : 0.f;
    float s1 = ez;
    for (int o = 32; o > 0; o >>= 1) s1 += __shfl_xor(s1, o);
    float zh = zhat[r];
    float mx2 = fmaxf(mx, zh);
    float denom = s1 * expf(mx - mx2) + expf(zh - mx2);
    float beta = expf(zh - mx2) / denom;
    if (lane < SS) alpha[lane] = ez / s1;
    __syncthreads();
    for (int d = lane; d < H2; d += 64) {
        float cv = 0.f;
#pragma unroll 8
        for (int s2 = 0; s2 < SS; ++s2)
            cv += alpha[s2] * us2f(U[(size_t)(b * SS + s2) * H2 + d]);
        float sv = us2f(sB[(size_t)r * H2 + d]);
        G[(size_t)r * G4 + H2 + d] = f2us(beta * sv + (1.f - beta) * cv);
    }
}
__global__ __launch_bounds__(256)
void logit_k(const u16* __restrict__ G, const u16* __restrict__ Mb,
             const u16* __restrict__ Wout, const float* __restrict__ boutF,
             void* __restrict__ out, const int* __restrict__ flag) {
    int r = blockIdx.x * 4 + (threadIdx.x >> 6);
    if (r >= BT) return;
    int lane = threadIdx.x & 63;
    float acc[TAGS_] = {0, 0, 0, 0, 0, 0, 0};
    for (int k = lane; k < 1536; k += 64) {
        float v = (k < G4) ? us2f(G[(size_t)r * G4 + k]) : us2f(Mb[(size_t)r * H2 + (k - G4)]);
#pragma unroll
        for (int tg = 0; tg < TAGS_; ++tg) acc[tg] += v * us2f(Wout[tg * 1536 + k]);
    }
#pragma unroll
    for (int tg = 0; tg < TAGS_; ++tg) {
        float s = acc[tg];
        for (int o = 32; o > 0; o >>= 1) s += __shfl_xor(s, o);
        acc[tg] = s;
    }
    if (lane == 0) {
        int bf = *flag;
#pragma unroll
        for (int tg = 0; tg < TAGS_; ++tg) {
            float v = acc[tg] + boutF[tg];
            if (bf) ((u16*)out)[(size_t)r * TAGS_ + tg] = f2us(v);
            else    ((float*)out)[(size_t)r * TAGS_ + tg] = v;
        }
    }
}

// ---------------------------------------------------------------------------
extern "C" void kernel_launch(void* const* d_in, const int* in_sizes, int n_in,
                              void* d_out, int out_size, void* d_ws, size_t ws_size,
                              hipStream_t stream)
{
    const void* x_text = d_in[0];
    const void* x_syn  = d_in[1];
    const int* len_ctx = (const int*)d_in[3];
    const void *Wih[6], *Whh[6], *bih[6], *bhh[6];
    for (int l = 0; l < 6; ++l) {
        Wih[l] = d_in[5 + l * 4 + 0];
        Whh[l] = d_in[5 + l * 4 + 1];
        bih[l] = d_in[5 + l * 4 + 2];
        bhh[l] = d_in[5 + l * 4 + 3];
    }
    const void* W_cWh = d_in[29];
    const void* W_cWu = d_in[30];
    const void* W_v   = d_in[31];
    const void* W_sWh = d_in[32];
    const void* W_sWu = d_in[33];
    const void* W_Ws  = d_in[34];
    const void* W_out = d_in[35];
    const void* b_out = d_in[36];
    (void)in_sizes; (void)n_in; (void)out_size;

    char* ws = (char*)d_ws;
    size_t off = 0;
    auto alloc = [&](size_t bytes) -> void* {
        void* p = ws + off;
        off += (bytes + 255) & ~(size_t)255;
        return p;
    };
    int*   flagB  = (int*)alloc(256);
    float* bsumAll = (float*)alloc((size_t)6 * G4 * 4);
    u16*   WsumB  = (u16*)alloc((size_t)H2 * H2 * 2);
    u16*   Ub     = (u16*)alloc((size_t)NSEQ * H2 * 2);
    u16*   Gb     = (u16*)alloc((size_t)BT * G4 * 2);
    u16*   mMb    = (u16*)alloc((size_t)BT * H2 * 2);
    float* cWhB   = (float*)alloc((size_t)BT * MDU_ * 4);
    float* cWuB   = (float*)alloc((size_t)NSEQ * MDU_ * 4);
    float* sWB    = (float*)alloc((size_t)BT * MDU_ * 4);
    float* zB     = (float*)alloc((size_t)BT * SS * 4);
    float* zhatB  = (float*)alloc((size_t)BT * 4);
    u16*   Wcwh16 = (u16*)alloc((size_t)MDU_ * H2 * 2);
    u16*   Wcwu16 = (u16*)alloc((size_t)MDU_ * H2 * 2);
    u16*   Wws16  = (u16*)alloc((size_t)MDU_ * H2 * 2);
    u16*   Wout16 = (u16*)alloc((size_t)TAGS_ * 1536 * 2);
    float* WvF    = (float*)alloc((size_t)MDU_ * 4);
    float* boutF  = (float*)alloc((size_t)TAGS_ * 4);
    u16*   WFall  = (u16*)alloc((size_t)6 * G4 * RR * 2);   // 6 x 512KB, contiguous
    u16*   WF[6];
    for (int l = 0; l < 6; ++l) WF[l] = WFall + (size_t)l * G4 * RR;
    float* bsum[6];
    for (int l = 0; l < 6; ++l) bsum[l] = bsumAll + (size_t)l * G4;
    u32*   cnts   = (u32*)alloc((size_t)128 * 64 * 4);      // per-WG flags, 64B lines
    u32*   hx32   = (u32*)alloc((size_t)128 * 2048 * 4);    // 1MB h exchange

    // choose synopsis mode by remaining workspace
    size_t fixedEnd = off;
    bool bigws = (ws_size >= fixedEnd + (size_t)81 * MB1);
    char* BIG = (char*)alloc(bigws ? (size_t)80 * MB1 : (size_t)24 * MB1);

    // BIG overlays, !bigws path (phases B/C/D; fit within first 24MB)
    u16*   bufA  = (u16*)BIG;
    u16*   bufB  = (u16*)(BIG + (size_t)8 * MB1);
    u16*   x16   = (u16*)(BIG + (size_t)16 * MB1);
    u16*   W16a  = (u16*)(BIG + (size_t)19 * MB1 + MB1 / 2);
    u16*   W16b  = (u16*)(BIG + (size_t)20 * MB1 + MB1 / 2);
    u16*   HprevB = (u16*)BIG;
    float* eBuf   = (float*)(BIG + (size_t)4 * MB1);
    u16*   sBuf   = (u16*)(BIG + (size_t)12 * MB1);
    u16*   mxWf  = (u16*)BIG;
    u16*   mxWb  = (u16*)(BIG + (size_t)8 * MB1);
    u16*   W16aD = (u16*)(BIG + (size_t)16 * MB1);
    u16*   W16bD = (u16*)(BIG + (size_t)18 * MB1);
    // bigws overlays (as round 9)
    u16*   mbufA = (u16*)BIG;
    u16*   mbufB = (u16*)(BIG + (size_t)32 * MB1);
    u16*   mx16  = (u16*)(BIG + (size_t)64 * MB1);
    u16*   mW16a = (u16*)(BIG + (size_t)78 * MB1);
    u16*   mW16b = (u16*)(BIG + (size_t)79 * MB1);
    u16*   bufAc = (u16*)(BIG + (size_t)64 * MB1);
    u16*   bufBc = (u16*)(BIG + (size_t)72 * MB1);
    u16*   x16c  = Gb;                      // 3.3MB in dead 8MB Gb
    u16*   W16ac = mMb;                     // 0.82MB in dead 4MB mMb
    u16*   W16bc = mMb + (size_t)G4 * DD;   // next 0.82MB

    auto cgrid = [](long n) { return dim3((unsigned)((n + 255) / 256)); };

    Ptr6 pBih, pBhh, pWhh;
    for (int l = 0; l < 6; ++l) { pBih.p[l] = bih[l]; pBhh.p[l] = bhh[l]; pWhh.p[l] = Whh[l]; }

    // ---- prep: dtype probe, then ALL weight transforms in one launch ----
    detect_k<<<dim3(1), dim3(256), 0, stream>>>(x_text, flagB);
    {
        long nprep = 51200L * 3 + 10752 + 100 + 7 + 6 * 1024 + 262144 + 6L * 262144 + 8192;
        prep_k<<<cgrid(nprep), dim3(256), 0, stream>>>(
            flagB, W_cWh, W_cWu, W_Ws, W_out, W_v, b_out, W_sWh, W_sWu,
            Wcwh16, Wcwu16, Wws16, Wout16, WvF, boutF, WsumB, bsumAll,
            pBih, pBhh, pWhh, WFall, cnts);
    }

    if (bigws) {
        // ---- fused input casts (syn + ctx), one launch ----
        {
            long ncast = (long)NSEQ * JJ * DD + 4L * G4 * DD + (long)BT * DD;
            castAB_k<<<cgrid(ncast), dim3(256), 0, stream>>>(
                x_syn, mx16, Wih[2], mW16a, Wih[3], mW16b,
                x_text, x16c, Wih[0], W16ac, Wih[1], W16bc, flagB);
        }
        // syn gemms (consume mx16/mW16*), then ctx gemms (reuse that region)
        gemm_bt<<<dim3(8, (NSEQ * JJ) / BM), dim3(256), 0, stream>>>(mx16, DD, mW16a, DD, mbufA, G4, bsum[2], NSEQ * JJ, G4, DD, 1);
        gemm_bt<<<dim3(8, (NSEQ * JJ) / BM), dim3(256), 0, stream>>>(mx16, DD, mW16b, DD, mbufB, G4, bsum[3], NSEQ * JJ, G4, DD, 1);
        gemm_bt<<<dim3(8, 32), dim3(256), 0, stream>>>(x16c, DD, W16ac, DD, bufAc, G4, bsum[0], BT, G4, DD, 1);
        gemm_bt<<<dim3(8, 32), dim3(256), 0, stream>>>(x16c, DD, W16bc, DD, bufBc, G4, bsum[1], BT, G4, DD, 1);
        // syn LSTM: 64 groups x 2 members, XCD-packed (G8=64, grid 128), grpBase 4
        lstm_coop<<<dim3(128), dim3(512), 0, stream>>>(
            mbufA, mbufB, WF[2], WF[3], JJ,
            Ub, H2, (u16*)nullptr, 0, (const int*)nullptr,
            0, 1, 0, hx32, cnts, 4, 32, 64);
        // ctx LSTM: 2 groups x 2 members (G8=8, grid 16), grpBase 0
        lstm_coop<<<dim3(16), dim3(512), 0, stream>>>(
            bufAc, bufBc, WF[0], WF[1], TT,
            Gb, G4, mMb, H2, len_ctx, 0, 0, 0, hx32, cnts, 0, 1, 8);
    } else {
        // chunked synopsis (4 chunks of 64 seqs), then context — fallback
        castbf_k<<<cgrid(G4 * DD), dim3(256), 0, stream>>>(Wih[2], 0, W16a, G4 * DD, flagB);
        castbf_k<<<cgrid(G4 * DD), dim3(256), 0, stream>>>(Wih[3], 0, W16b, G4 * DD, flagB);
        for (int c = 0; c < NSEQ / SCH; ++c) {
            long chunkElems = (long)SCH * JJ * DD;
            castbf_k<<<cgrid(chunkElems), dim3(256), 0, stream>>>(x_syn, (long)c * chunkElems, x16, chunkElems, flagB);
            gemm_bt<<<dim3(8, (SCH * JJ) / BM), dim3(256), 0, stream>>>(x16, DD, W16a, DD, bufA, G4, bsum[2], SCH * JJ, G4, DD, 1);
            gemm_bt<<<dim3(8, (SCH * JJ) / BM), dim3(256), 0, stream>>>(x16, DD, W16b, DD, bufB, G4, bsum[3], SCH * JJ, G4, DD, 1);
            lstm_coop<<<dim3(32), dim3(512), 0, stream>>>(
                bufA, bufB, WF[2], WF[3], JJ,
                Ub, H2, (u16*)nullptr, 0, (const int*)nullptr,
                0, 1, c * SCH, hx32, cnts, 4 + c * 16, 8, 16);
        }
        castbf_k<<<cgrid((long)BT * DD), dim3(256), 0, stream>>>(x_text, 0, x16, (long)BT * DD, flagB);
        castbf_k<<<cgrid(G4 * DD), dim3(256), 0, stream>>>(Wih[0], 0, W16a, G4 * DD, flagB);
        castbf_k<<<cgrid(G4 * DD), dim3(256), 0, stream>>>(Wih[1], 0, W16b, G4 * DD, flagB);
        gemm_bt<<<dim3(8, 32), dim3(256), 0, stream>>>(x16, DD, W16a, DD, bufA, G4, bsum[0], BT, G4, DD, 1);
        gemm_bt<<<dim3(8, 32), dim3(256), 0, stream>>>(x16, DD, W16b, DD, bufB, G4, bsum[1], BT, G4, DD, 1);
        lstm_coop<<<dim3(16), dim3(512), 0, stream>>>(
            bufA, bufB, WF[0], WF[1], TT,
            Gb, G4, mMb, H2, len_ctx, 0, 0, 0, hx32, cnts, 0, 1, 8);
    }

    // ---- phase C: attention ----
    gemm_bt<<<dim3(1, 32), dim3(256), 0, stream>>>(Gb, G4, Wcwh16, H2, cWhB, MDU_, nullptr, BT, MDU_, H2, 0);
    gemm_bt<<<dim3(1, 2),  dim3(256), 0, stream>>>(Ub, H2, Wcwu16, H2, cWuB, MDU_, nullptr, NSEQ, MDU_, H2, 0);
    hprev_k<<<cgrid(BT * H2), dim3(256), 0, stream>>>(Gb, HprevB);
    gemm_bt<<<dim3(4, 32), dim3(256), 0, stream>>>(HprevB, H2, WsumB, H2, eBuf, H2, nullptr, BT, H2, H2, 0);
    s_k<<<cgrid(BT * H2), dim3(256), 0, stream>>>(eBuf, mMb, sBuf);
    gemm_bt<<<dim3(1, 32), dim3(256), 0, stream>>>(sBuf, H2, Wws16, H2, sWB, MDU_, nullptr, BT, MDU_, H2, 0);
    z_k<<<cgrid(BT * SS), dim3(256), 0, stream>>>(cWhB, cWuB, WvF, zB);
    zhat_k<<<cgrid(BT), dim3(256), 0, stream>>>(sWB, cWhB, WvF, zhatB);
    attn_mix_k<<<dim3(BT), dim3(64), 0, stream>>>(zB, zhatB, Ub, sBuf, Gb);

    // ---- phase D: layer-2 LSTMs over G -> M (into mMb), groups 2,3 ----
    cast3_k<<<cgrid(2L * G4 * G4), dim3(256), 0, stream>>>(
        Wih[4], W16aD, (long)G4 * G4, Wih[5], W16bD, (long)G4 * G4,
        nullptr, nullptr, 0, flagB);
    gemm_bt<<<dim3(8, 32), dim3(256), 0, stream>>>(Gb, G4, W16aD, G4, mxWf, G4, bsum[4], BT, G4, G4, 1);
    gemm_bt<<<dim3(8, 32), dim3(256), 0, stream>>>(Gb, G4, W16bD, G4, mxWb, G4, bsum[5], BT, G4, G4, 1);
    lstm_coop<<<dim3(16), dim3(512), 0, stream>>>(
        mxWf, mxWb, WF[4], WF[5], TT,
        mMb, H2, (u16*)nullptr, 0, (const int*)nullptr, 1, 0, 0, hx32, cnts, 2, 1, 8);

    // ---- output ----
    logit_k<<<dim3(BT / 4), dim3(256), 0, stream>>>(Gb, mMb, Wout16, boutF, d_out, flagB);
}

// Round 12
// 3940.656 us; speedup vs baseline: 1.1806x; 1.1806x over previous
//
#include <hip/hip_runtime.h>
#include <math.h>
#include <stddef.h>

// ---------------------------------------------------------------------------
// ATT_SYN: bi-LSTM encoder + synopsis attention + 2nd bi-LSTM + tag head.
// B=8 T=512 S=32 J=64 D=400 R=256 MDU=100 TAGS=7
// Recurrence: round-9-verified cooperative 4-WG-per-direction kernel
// (Whh in 128 VGPRs/lane; per-WG 64B flag lines; tid0 relaxed poll +
// acquire fence + barrier; deferred outputs + x prefetch under the spin).
// Round-12 (structural census closed the LSTM: 7 variants, round-9 wins):
//   - fwd/bwd GEMM pairs merged into single N=2048 GEMMs (syn/ctx/D):
//     halves A reads, -3 dispatches; lstm takes an xW strideX param
//   - z_k + zhat_k fused into one segmented launch
//   - host-side fusions kept (prep_k / castAB_k / cast3_k, fast phase-C)
// ---------------------------------------------------------------------------

#define BB 8
#define TT 512
#define SS 32
#define JJ 64
#define DD 400
#define RR 256
#define G4 1024
#define N2 2048
#define H2 512
#define MDU_ 100
#define TAGS_ 7
#define BT (BB*TT)
#define NSEQ (BB*SS)
#define SCH 64
#define MB1 (1024*1024)

typedef __attribute__((ext_vector_type(8))) short short8;
typedef __attribute__((ext_vector_type(4))) float floatx4;
typedef __attribute__((ext_vector_type(4))) unsigned int u32x4;
typedef unsigned short u16;
typedef unsigned int u32;

struct Ptr6 { const void* p[6]; };

__device__ __forceinline__ float us2f(u16 u) {
    unsigned int v = ((unsigned int)u) << 16;
    return __builtin_bit_cast(float, v);
}
__device__ __forceinline__ u16 f2us(float f) {
    unsigned int v = __builtin_bit_cast(unsigned int, f);
    v += 0x7FFFu + ((v >> 16) & 1u);
    return (u16)(v >> 16);
}
__device__ __forceinline__ float ldin(const void* p, long i, int bf) {
    return bf ? us2f(((const u16*)p)[i]) : ((const float*)p)[i];
}
// fast activations (NaN-safe; recurrence path since round 2)
__device__ __forceinline__ float sigm_f(float x) { return 1.0f / (1.0f + __expf(-x)); }
__device__ __forceinline__ float tanh_f(float x) {
    float e = __expf(-2.0f * fabsf(x));
    float t = (1.0f - e) / (1.0f + e);
    return copysignf(t, x);
}

// ---- dtype probe ----
__global__ void detect_k(const void* x, int* flag) {
    __shared__ int cnt;
    if (threadIdx.x == 0) cnt = 0;
    __syncthreads();
    u16 lo = ((const u16*)x)[threadIdx.x * 2];
    int e = (lo >> 7) & 0xFF;
    if (e >= 118 && e <= 131) atomicAdd(&cnt, 1);
    __syncthreads();
    if (threadIdx.x == 0) *flag = (cnt > 128) ? 1 : 0;
}
__global__ void castbf_k(const void* src, long off, u16* dst, long n, const int* flag) {
    long i = (long)blockIdx.x * 256 + threadIdx.x;
    if (i < n) dst[i] = (*flag) ? ((const u16*)src)[off + i] : f2us(((const float*)src)[off + i]);
}

// ---- fused prep: all weight transforms + counter zeroing, one launch ----
__global__ void prep_k(const int* __restrict__ flag,
    const void* Wcwh, const void* Wcwu, const void* Wws, const void* Wout,
    const void* Wv, const void* bout, const void* WsWh, const void* WsWu,
    u16* Wcwh16, u16* Wcwu16, u16* Wws16, u16* Wout16,
    float* WvF, float* boutF, u16* WsumB, float* bsumAll,
    Ptr6 bih, Ptr6 bhh, Ptr6 whh, u16* WFall, u32* cnts)
{
    const int bf = *flag;
    long i = (long)blockIdx.x * 256 + threadIdx.x;
    if (i < 51200) { Wcwh16[i] = f2us(ldin(Wcwh, i, bf)); return; }
    i -= 51200;
    if (i < 51200) { Wcwu16[i] = f2us(ldin(Wcwu, i, bf)); return; }
    i -= 51200;
    if (i < 51200) { Wws16[i] = f2us(ldin(Wws, i, bf)); return; }
    i -= 51200;
    if (i < 10752) { Wout16[i] = f2us(ldin(Wout, i, bf)); return; }
    i -= 10752;
    if (i < 100) { WvF[i] = ldin(Wv, i, bf); return; }
    i -= 100;
    if (i < 7) { boutF[i] = ldin(bout, i, bf); return; }
    i -= 7;
    if (i < 6 * 1024) {
        int l = (int)(i >> 10), k = (int)(i & 1023);
        bsumAll[l * 1024 + k] = ldin(bih.p[l], k, bf) + ldin(bhh.p[l], k, bf);
        return;
    }
    i -= 6 * 1024;
    if (i < 262144) { WsumB[i] = f2us(ldin(WsWh, i, bf) + ldin(WsWu, i, bf)); return; }
    i -= 262144;
    if (i < 6L * 262144) {
        // Whh [1024,256] -> pre-swizzled MFMA B-fragments (4-slice partition):
        // ii = ((((s*4+w)*4+t)*8+c)*64+ln)*8+j
        int l  = (int)(i >> 18);
        int ii = (int)(i & 262143);
        int j  = ii & 7;
        int ln = (ii >> 3) & 63;
        int c  = (ii >> 9) & 7;
        int t  = (ii >> 12) & 3;
        int w  = (ii >> 14) & 3;
        int s  = (ii >> 16) & 3;
        int n_g = w * 256 + s * 64 + t * 16 + (ln & 15);
        int k   = c * 32 + (ln >> 4) * 8 + j;
        WFall[(size_t)l * 262144 + ii] = f2us(ldin(whh.p[l], (long)n_g * 256 + k, bf));
        return;
    }
    i -= 6L * 262144;
    if (i < 8192) cnts[i] = 0u;
}

// ---- fused A+B input casts (bigws path), one launch.
//      Weight pairs land ADJACENT so merged N=2048 GEMMs see concat rows.
__global__ void castAB_k(const void* xsyn, u16* mx16,
                         const void* wih2, u16* mW16ab,
                         const void* wih3,
                         const void* xtext, u16* x16c,
                         const void* wih0, u16* W16abc,
                         const void* wih1,
                         const int* __restrict__ flag)
{
    const int bf = *flag;
    long i = (long)blockIdx.x * 256 + threadIdx.x;
    const long nsyn = (long)NSEQ * JJ * DD;
    const long nw   = (long)G4 * DD;
    const long ntxt = (long)BT * DD;
    if (i < nsyn) { mx16[i] = f2us(ldin(xsyn, i, bf)); return; }
    i -= nsyn;
    if (i < nw) { mW16ab[i] = f2us(ldin(wih2, i, bf)); return; }
    i -= nw;
    if (i < nw) { mW16ab[nw + i] = f2us(ldin(wih3, i, bf)); return; }
    i -= nw;
    if (i < ntxt) { x16c[i] = f2us(ldin(xtext, i, bf)); return; }
    i -= ntxt;
    if (i < nw) { W16abc[i] = f2us(ldin(wih0, i, bf)); return; }
    i -= nw;
    if (i < nw) { W16abc[nw + i] = f2us(ldin(wih1, i, bf)); return; }
}

// ---- generic fused 3-segment cast ----
__global__ void cast3_k(const void* s0, u16* d0, long n0,
                        const void* s1, u16* d1, long n1,
                        const void* s2, u16* d2, long n2,
                        const int* __restrict__ flag)
{
    const int bf = *flag;
    long i = (long)blockIdx.x * 256 + threadIdx.x;
    if (i < n0) { d0[i] = f2us(ldin(s0, i, bf)); return; }
    i -= n0;
    if (i < n1) { d1[i] = f2us(ldin(s1, i, bf)); return; }
    i -= n1;
    if (i < n2) { d2[i] = f2us(ldin(s2, i, bf)); return; }
}

// ---------------------------------------------------------------------------
// GEMM: C[M,N] = A[M,K] @ W[N,K]^T (+bias); A,W bf16; C f32 or bf16.
// ---------------------------------------------------------------------------
#define BM 128
#define BN 128
#define BK 32
#define LDT 40

__global__ __launch_bounds__(256)
void gemm_bt(const u16* __restrict__ A, int lda,
             const u16* __restrict__ W, int ldw,
             void* __restrict__ C, int ldc,
             const float* __restrict__ bias,
             int M, int N, int K, int outBf16)
{
    __shared__ alignas(16) short As[BM * LDT];
    __shared__ alignas(16) short Bs[BN * LDT];
    const int tid  = threadIdx.x;
    const int m0   = blockIdx.y * BM;
    const int n0   = blockIdx.x * BN;
    const int lane = tid & 63;
    const int wave = tid >> 6;
    const int wm   = wave >> 1, wn = wave & 1;
    const int quad = lane >> 4, mrow = lane & 15;

    floatx4 acc[4][4];
#pragma unroll
    for (int i = 0; i < 4; ++i)
#pragma unroll
        for (int j = 0; j < 4; ++j) { floatx4 z4 = {0.f,0.f,0.f,0.f}; acc[i][j] = z4; }

    for (int k0 = 0; k0 < K; k0 += BK) {
#pragma unroll
        for (int cc = 0; cc < 2; ++cc) {
            int c   = tid + cc * 256;
            int row = c >> 2;
            int kc  = (c & 3) << 3;
            int gk  = k0 + kc;
            {
                int gr = m0 + row;
                short8 v;
                if (gr < M && gk + 8 <= K) {
                    v = *(const short8*)(A + (size_t)gr * lda + gk);
                } else {
#pragma unroll
                    for (int e = 0; e < 8; ++e)
                        v[e] = (gr < M && (gk + e) < K) ? (short)A[(size_t)gr * lda + gk + e] : (short)0;
                }
                *(short8*)&As[row * LDT + kc] = v;
            }
            {
                int gn = n0 + row;
                short8 v;
                if (gn < N && gk + 8 <= K) {
                    v = *(const short8*)(W + (size_t)gn * ldw + gk);
                } else {
#pragma unroll
                    for (int e = 0; e < 8; ++e)
                        v[e] = (gn < N && (gk + e) < K) ? (short)W[(size_t)gn * ldw + gk + e] : (short)0;
                }
                *(short8*)&Bs[row * LDT + kc] = v;
            }
        }
        __syncthreads();

        short8 af[4], bf[4];
#pragma unroll
        for (int i = 0; i < 4; ++i)
            af[i] = *(const short8*)&As[(wm * 64 + i * 16 + mrow) * LDT + quad * 8];
#pragma unroll
        for (int j = 0; j < 4; ++j)
            bf[j] = *(const short8*)&Bs[(wn * 64 + j * 16 + mrow) * LDT + quad * 8];
#pragma unroll
        for (int i = 0; i < 4; ++i)
#pragma unroll
            for (int j = 0; j < 4; ++j)
                acc[i][j] = __builtin_amdgcn_mfma_f32_16x16x32_bf16(af[i], bf[j], acc[i][j], 0, 0, 0);
        __syncthreads();
    }

#pragma unroll
    for (int i = 0; i < 4; ++i)
#pragma unroll
        for (int j = 0; j < 4; ++j)
#pragma unroll
            for (int r = 0; r < 4; ++r) {
                int row = m0 + wm * 64 + i * 16 + quad * 4 + r;
                int col = n0 + wn * 64 + j * 16 + mrow;
                if (row < M && col < N) {
                    float v = acc[i][j][r];
                    if (bias) v += bias[col];
                    if (outBf16) ((u16*)C)[(size_t)row * ldc + col] = f2us(v);
                    else         ((float*)C)[(size_t)row * ldc + col] = v;
                }
            }
}

// ---------------------------------------------------------------------------
// Cooperative LSTM — round-9-verified structure. Flat grid of 4*G8 WGs:
// member s = wgid/G8 (slice), g = wgid%G8 (group = dir*nb+bat, active if
// g < 2*nb). G8 % 8 == 0 -> group members share wgid mod 8 -> same XCD
// (heuristic only). Each WG: 256 thr (4 waves), wave w = gate type, 64x256
// bf16 Whh slice in 128 VGPRs. M=8 seqs/group. xW row stride is strideX
// (2048 for merged fwd|bwd gate buffers, G4 for the legacy layout).
// Per-step sync: per-WG flag on its own 64B line (release store after
// drain+barrier); ALL waves then issue deferred outputs + x prefetch
// (flushes the flag store); tid0 relaxed poll + acquire fence + barrier.
// c-state in registers.
// ---------------------------------------------------------------------------
__global__ __launch_bounds__(256, 1)
void lstm_coop(const u16* __restrict__ xWf, const u16* __restrict__ xWb,
               const u16* __restrict__ WFf, const u16* __restrict__ WFb,
               int L, int strideX,
               u16* __restrict__ hOut, int hStride,
               u16* __restrict__ cOut, int cStride,
               const int* __restrict__ lenp,
               int writeAtSource, int lastOnly, int seqBase,
               u32* __restrict__ hx32, u32* __restrict__ flags,
               int grpBase, int nb, int G8)
{
    const int wgid = blockIdx.x;
    const int s    = wgid / G8;          // slice (gate cols s*64..s*64+63)
    const int g    = wgid - s * G8;      // group id
    if (g >= 2 * nb) return;
    const int dir  = g / nb;
    const int bat  = g - dir * nb;
    const int tid = threadIdx.x;
    const int wv  = tid >> 6;            // gate type i,f,g,o
    const int ln  = tid & 63;
    const int q   = ln >> 4, m = ln & 15;
    const u16* xW = dir ? xWb : xWf;
    const u16* WF = dir ? WFb : WFf;
    const int grp = grpBase + g;
    u32* flg = flags + (size_t)grp * 64;    // 4 slots, one 64B line each
    u32* hx  = hx32 + (size_t)grp * 2048;   // [2 parity][8 seq][128 u32]

    __shared__ float g_s[4 * 8 * 64];

    // resident B fragments: 4 N-tiles x 8 K-chunks, 16B/lane each = 128 VGPRs
    short8 bw[4][8];
    {
        const u16* wb = WF + ((size_t)(s * 4 + wv) * 32) * 512 + ln * 8;
#pragma unroll
        for (int t4 = 0; t4 < 4; ++t4)
#pragma unroll
            for (int c = 0; c < 8; ++c)
                bw[t4][c] = *(const short8*)(wb + (size_t)(t4 * 8 + c) * 512);
    }

    const int seqU = tid >> 5;             // update phase: seq 0..7
    const int j0   = (tid & 31) * 2;       // local col pair within slice
    const int gcol = s * 64 + j0;          // global gate col
    const int mylen = lenp ? lenp[bat * 8 + seqU] : 0x7fffffff;
    float cR0 = 0.f, cR1 = 0.f;            // c-state: exclusively this thread's

    // preload x gate values for t=0
    u32 px0, px1, px2, px3;
    {
        const int tt0 = dir ? (L - 1) : 0;
        const u16* xr = xW + (((size_t)(bat * 8 + seqU)) * L + tt0) * strideX + gcol;
        px0 = *(const u32*)xr;
        px1 = *(const u32*)(xr + 256);
        px2 = *(const u32*)(xr + 512);
        px3 = *(const u32*)(xr + 768);
    }

    for (int t = 0; t < L; ++t) {
        const int tt = dir ? (L - 1 - t) : t;
        // ---- A fragments from hx[(t-1)&1]
        short8 a[8];
        if (t > 0) {
            const u32* hp = hx + ((t - 1) & 1) * 1024 + m * 128;
#pragma unroll
            for (int c = 0; c < 8; ++c) {
                if (m < 8) {
                    u32x4 v = *(const u32x4*)(hp + c * 16 + q * 4);
                    a[c] = __builtin_bit_cast(short8, v);
                } else {
                    short8 z = {0,0,0,0,0,0,0,0}; a[c] = z;
                }
            }
        } else {
            short8 z = {0,0,0,0,0,0,0,0};
#pragma unroll
            for (int c = 0; c < 8; ++c) a[c] = z;
        }
        floatx4 acc[4];
#pragma unroll
        for (int t4 = 0; t4 < 4; ++t4) { floatx4 z4 = {0.f,0.f,0.f,0.f}; acc[t4] = z4; }
#pragma unroll
        for (int c = 0; c < 8; ++c)
#pragma unroll
            for (int t4 = 0; t4 < 4; ++t4)
                acc[t4] = __builtin_amdgcn_mfma_f32_16x16x32_bf16(a[c], bw[t4][c], acc[t4], 0, 0, 0);
        // C layout: seq = q*4+r (valid q<2), col n = t4*16 + m
        if (q < 2) {
#pragma unroll
            for (int t4 = 0; t4 < 4; ++t4)
#pragma unroll
                for (int r = 0; r < 4; ++r)
                    g_s[(wv * 8 + q * 4 + r) * 64 + t4 * 16 + m] = acc[t4][r];
        }
        __syncthreads();
        // ---- gate fuse + state update: thread -> (seqU, cols gcol..gcol+1)
        float hn0, hn1, cn0, cn1;
        {
            float i0 = g_s[(0 * 8 + seqU) * 64 + j0]     + us2f((u16)(px0 & 0xffffu));
            float i1 = g_s[(0 * 8 + seqU) * 64 + j0 + 1] + us2f((u16)(px0 >> 16));
            float f0 = g_s[(1 * 8 + seqU) * 64 + j0]     + us2f((u16)(px1 & 0xffffu));
            float f1 = g_s[(1 * 8 + seqU) * 64 + j0 + 1] + us2f((u16)(px1 >> 16));
            float g0 = g_s[(2 * 8 + seqU) * 64 + j0]     + us2f((u16)(px2 & 0xffffu));
            float g1 = g_s[(2 * 8 + seqU) * 64 + j0 + 1] + us2f((u16)(px2 >> 16));
            float o0 = g_s[(3 * 8 + seqU) * 64 + j0]     + us2f((u16)(px3 & 0xffffu));
            float o1 = g_s[(3 * 8 + seqU) * 64 + j0 + 1] + us2f((u16)(px3 >> 16));
            cn0 = sigm_f(f0) * cR0 + sigm_f(i0) * tanh_f(g0);
            cn1 = sigm_f(f1) * cR1 + sigm_f(i1) * tanh_f(g1);
            hn0 = sigm_f(o0) * tanh_f(cn0);
            hn1 = sigm_f(o1) * tanh_f(cn1);
            cR0 = cn0;
            cR1 = cn1;
            u32 hpack = (u32)f2us(hn0) | ((u32)f2us(hn1) << 16);
            __hip_atomic_store(hx + (t & 1) * 1024 + seqU * 128 + (gcol >> 1),
                               hpack, __ATOMIC_RELAXED, __HIP_MEMORY_SCOPE_AGENT);
        }
        // drain own agent-scope hx store, then barrier, then signal
        asm volatile("s_waitcnt vmcnt(0)" ::: "memory");
        __syncthreads();
        const bool last = (t == L - 1);
        if (tid == 0 && !last)
            __hip_atomic_store(&flg[s * 16], (u32)(t + 1),
                               __ATOMIC_RELEASE, __HIP_MEMORY_SCOPE_AGENT);
        // ---- deferred global outputs: overlap the spin (also flushes flag)
        if (!lastOnly) {
            int wr = writeAtSource ? tt : t;
            float mk = (wr >= mylen) ? 0.f : 1.f;
            size_t ro = ((size_t)(bat * 8 + seqU)) * L + wr;
            u32 hp2 = (u32)f2us(hn0 * mk) | ((u32)f2us(hn1 * mk) << 16);
            *(u32*)(hOut + ro * hStride + dir * RR + gcol) = hp2;
            if (cOut) {
                u32 cp2 = (u32)f2us(cn0 * mk) | ((u32)f2us(cn1 * mk) << 16);
                *(u32*)(cOut + ro * cStride + dir * RR + gcol) = cp2;
            }
        } else if (last) {
            size_t ro = (size_t)(seqBase + bat * 8 + seqU);
            u32 hp2 = (u32)f2us(hn0) | ((u32)f2us(hn1) << 16);
            *(u32*)(hOut + ro * hStride + dir * RR + gcol) = hp2;
        }
        if (!last) {
            // prefetch next-step x gate values (in flight during the spin)
            {
                const int tn = dir ? (L - 2 - t) : (t + 1);
                const u16* xr = xW + (((size_t)(bat * 8 + seqU)) * L + tn) * strideX + gcol;
                px0 = *(const u32*)xr;
                px1 = *(const u32*)(xr + 256);
                px2 = *(const u32*)(xr + 512);
                px3 = *(const u32*)(xr + 768);
            }
            // tid0-only relaxed poll (minimal coherence-point traffic);
            // acquire fence on exit invalidates this CU's L1 so all waves'
            // hx reloads (after the barrier) fetch fresh lines.
            if (tid == 0) {
                const u32 tgt = (u32)(t + 1);
                long guard = 0;
                for (;;) {
                    u32 f0 = __hip_atomic_load(&flg[0],  __ATOMIC_RELAXED, __HIP_MEMORY_SCOPE_AGENT);
                    u32 f1 = __hip_atomic_load(&flg[16], __ATOMIC_RELAXED, __HIP_MEMORY_SCOPE_AGENT);
                    u32 f2 = __hip_atomic_load(&flg[32], __ATOMIC_RELAXED, __HIP_MEMORY_SCOPE_AGENT);
                    u32 f3 = __hip_atomic_load(&flg[48], __ATOMIC_RELAXED, __HIP_MEMORY_SCOPE_AGENT);
                    if (f0 >= tgt && f1 >= tgt && f2 >= tgt && f3 >= tgt) break;
                    if (++guard > (1L << 18)) break;   // diagnostic bail
                    if (guard > 32) __builtin_amdgcn_s_sleep(1);
                }
                __builtin_amdgcn_fence(__ATOMIC_ACQUIRE, "agent");
            }
            __syncthreads();
        }
    }
}

// ------------------------- small fused kernels -----------------------------
__global__ void hprev_k(const u16* __restrict__ G, u16* __restrict__ Hp) {
    int idx = blockIdx.x * 256 + threadIdx.x;
    if (idx < BT * H2) {
        int r = idx >> 9, d = idx & 511;
        int t = r & (TT - 1);
        Hp[idx] = (t == 0) ? (u16)0 : G[(size_t)(r - 1) * G4 + d];
    }
}
__global__ void s_k(const float* __restrict__ e, const u16* __restrict__ mB,
                    u16* __restrict__ sB) {
    int i = blockIdx.x * 256 + threadIdx.x;
    if (i < BT * H2) sB[i] = f2us(sigm_f(e[i]) * tanh_f(us2f(mB[i])));
}
// fused z (BT*SS) + zhat (BT), one launch
__global__ void zz_k(const float* __restrict__ cWh, const float* __restrict__ cWu,
                     const float* __restrict__ sW, const float* __restrict__ Wv,
                     float* __restrict__ z, float* __restrict__ zhat) {
    long idx = (long)blockIdx.x * 256 + threadIdx.x;
    if (idx < (long)BT * SS) {
        int r = (int)(idx >> 5), s = (int)(idx & 31);
        int b = r >> 9;
        const float* ph = cWh + (size_t)r * MDU_;
        const float* pu = cWu + (size_t)(b * SS + s) * MDU_;
        float acc = 0.f;
#pragma unroll 4
        for (int j = 0; j < MDU_; ++j) acc += tanh_f(ph[j] + pu[j]) * Wv[j];
        z[idx] = acc;
        return;
    }
    idx -= (long)BT * SS;
    if (idx < BT) {
        int r = (int)idx;
        const float* ps = sW + (size_t)r * MDU_;
        const float* ph = cWh + (size_t)r * MDU_;
        float acc = 0.f;
#pragma unroll 4
        for (int j = 0; j < MDU_; ++j) acc += tanh_f(ps[j] + ph[j]) * Wv[j];
        zhat[r] = acc;
    }
}
__global__ __launch_bounds__(64)
void attn_mix_k(const float* __restrict__ z, const float* __restrict__ zhat,
                const u16* __restrict__ U, const u16* __restrict__ sB,
                u16* __restrict__ G) {
    int r = blockIdx.x;
    int lane = threadIdx.x;
    int b = r >> 9;
    __shared__ float alpha[SS];
    float zv = (lane < SS) ? z[(size_t)r * SS + lane] : -1e30f;
    float mx = zv;
    for (int o = 32; o > 0; o >>= 1) mx = fmaxf(mx, __shfl_xor(mx, o));
    float ez = (lane < SS) ? expf(zv - mx) : 0.f;
    float s1 = ez;
    for (int o = 32; o > 0; o >>= 1) s1 += __shfl_xor(s1, o);
    float zh = zhat[r];
    float mx2 = fmaxf(mx, zh);
    float denom = s1 * expf(mx - mx2) + expf(zh - mx2);
    float beta = expf(zh - mx2) / denom;
    if (lane < SS) alpha[lane] = ez / s1;
    __syncthreads();
    for (int d = lane; d < H2; d += 64) {
        float cv = 0.f;
#pragma unroll 8
        for (int s2 = 0; s2 < SS; ++s2)
            cv += alpha[s2] * us2f(U[(size_t)(b * SS + s2) * H2 + d]);
        float sv = us2f(sB[(size_t)r * H2 + d]);
        G[(size_t)r * G4 + H2 + d] = f2us(beta * sv + (1.f - beta) * cv);
    }
}
__global__ __launch_bounds__(256)
void logit_k(const u16* __restrict__ G, const u16* __restrict__ Mb,
             const u16* __restrict__ Wout, const float* __restrict__ boutF,
             void* __restrict__ out, const int* __restrict__ flag) {
    int r = blockIdx.x * 4 + (threadIdx.x >> 6);
    if (r >= BT) return;
    int lane = threadIdx.x & 63;
    float acc[TAGS_] = {0, 0, 0, 0, 0, 0, 0};
    for (int k = lane; k < 1536; k += 64) {
        float v = (k < G4) ? us2f(G[(size_t)r * G4 + k]) : us2f(Mb[(size_t)r * H2 + (k - G4)]);
#pragma unroll
        for (int tg = 0; tg < TAGS_; ++tg) acc[tg] += v * us2f(Wout[tg * 1536 + k]);
    }
#pragma unroll
    for (int tg = 0; tg < TAGS_; ++tg) {
        float s = acc[tg];
        for (int o = 32; o > 0; o >>= 1) s += __shfl_xor(s, o);
        acc[tg] = s;
    }
    if (lane == 0) {
        int bf = *flag;
#pragma unroll
        for (int tg = 0; tg < TAGS_; ++tg) {
            float v = acc[tg] + boutF[tg];
            if (bf) ((u16*)out)[(size_t)r * TAGS_ + tg] = f2us(v);
            else    ((float*)out)[(size_t)r * TAGS_ + tg] = v;
        }
    }
}

// ---------------------------------------------------------------------------
extern "C" void kernel_launch(void* const* d_in, const int* in_sizes, int n_in,
                              void* d_out, int out_size, void* d_ws, size_t ws_size,
                              hipStream_t stream)
{
    const void* x_text = d_in[0];
    const void* x_syn  = d_in[1];
    const int* len_ctx = (const int*)d_in[3];
    const void *Wih[6], *Whh[6], *bih[6], *bhh[6];
    for (int l = 0; l < 6; ++l) {
        Wih[l] = d_in[5 + l * 4 + 0];
        Whh[l] = d_in[5 + l * 4 + 1];
        bih[l] = d_in[5 + l * 4 + 2];
        bhh[l] = d_in[5 + l * 4 + 3];
    }
    const void* W_cWh = d_in[29];
    const void* W_cWu = d_in[30];
    const void* W_v   = d_in[31];
    const void* W_sWh = d_in[32];
    const void* W_sWu = d_in[33];
    const void* W_Ws  = d_in[34];
    const void* W_out = d_in[35];
    const void* b_out = d_in[36];
    (void)in_sizes; (void)n_in; (void)out_size;

    char* ws = (char*)d_ws;
    size_t off = 0;
    auto alloc = [&](size_t bytes) -> void* {
        void* p = ws + off;
        off += (bytes + 255) & ~(size_t)255;
        return p;
    };
    int*   flagB  = (int*)alloc(256);
    float* bsumAll = (float*)alloc((size_t)6 * G4 * 4);
    u16*   WsumB  = (u16*)alloc((size_t)H2 * H2 * 2);
    u16*   Ub     = (u16*)alloc((size_t)NSEQ * H2 * 2);
    u16*   Gb     = (u16*)alloc((size_t)BT * G4 * 2);
    u16*   mMb    = (u16*)alloc((size_t)BT * H2 * 2);
    float* cWhB   = (float*)alloc((size_t)BT * MDU_ * 4);
    float* cWuB   = (float*)alloc((size_t)NSEQ * MDU_ * 4);
    float* sWB    = (float*)alloc((size_t)BT * MDU_ * 4);
    float* zB     = (float*)alloc((size_t)BT * SS * 4);
    float* zhatB  = (float*)alloc((size_t)BT * 4);
    u16*   Wcwh16 = (u16*)alloc((size_t)MDU_ * H2 * 2);
    u16*   Wcwu16 = (u16*)alloc((size_t)MDU_ * H2 * 2);
    u16*   Wws16  = (u16*)alloc((size_t)MDU_ * H2 * 2);
    u16*   Wout16 = (u16*)alloc((size_t)TAGS_ * 1536 * 2);
    float* WvF    = (float*)alloc((size_t)MDU_ * 4);
    float* boutF  = (float*)alloc((size_t)TAGS_ * 4);
    u16*   WFall  = (u16*)alloc((size_t)6 * G4 * RR * 2);   // 6 x 512KB, contiguous
    u16*   WF[6];
    for (int l = 0; l < 6; ++l) WF[l] = WFall + (size_t)l * G4 * RR;
    float* bsum[6];
    for (int l = 0; l < 6; ++l) bsum[l] = bsumAll + (size_t)l * G4;
    u32*   cnts   = (u32*)alloc((size_t)128 * 64 * 4);      // per-WG flags, 64B lines
    u32*   hx32   = (u32*)alloc((size_t)128 * 2048 * 4);    // 1MB h exchange

    // choose synopsis mode by remaining workspace
    size_t fixedEnd = off;
    bool bigws = (ws_size >= fixedEnd + (size_t)81 * MB1);
    char* BIG = (char*)alloc(bigws ? (size_t)80 * MB1 : (size_t)24 * MB1);

    // BIG overlays, !bigws path (phases B/C/D; fit within first 24MB)
    u16*   bufA  = (u16*)BIG;
    u16*   bufB  = (u16*)(BIG + (size_t)8 * MB1);
    u16*   x16   = (u16*)(BIG + (size_t)16 * MB1);
    u16*   W16a  = (u16*)(BIG + (size_t)19 * MB1 + MB1 / 2);
    u16*   W16b  = (u16*)(BIG + (size_t)20 * MB1 + MB1 / 2);
    u16*   HprevB = (u16*)BIG;
    float* eBuf   = (float*)(BIG + (size_t)4 * MB1);
    u16*   sBuf   = (u16*)(BIG + (size_t)12 * MB1);
    u16*   mxW   = (u16*)BIG;                           // D: [BT][2048] = 16MB
    u16*   W16aD = (u16*)(BIG + (size_t)16 * MB1);      // D: concat W, 4MB
    // bigws overlays:
    //  syn xW (merged): msynW BIG[0,64MB) = [NSEQ*JJ][2048]
    //  syn inputs: mx16 64..77.2MB, mW16ab 78..79.6MB (dead after syn gemm)
    //  ctx xW (merged): ctxW BIG[64,80MB) = [BT][2048] (after syn gemm)
    //  ctx cast scratch borrows dead Gb/mMb
    u16*   msynW = (u16*)BIG;
    u16*   mx16  = (u16*)(BIG + (size_t)64 * MB1);
    u16*   mW16ab = (u16*)(BIG + (size_t)78 * MB1);      // 2048x400 concat
    u16*   ctxW  = (u16*)(BIG + (size_t)64 * MB1);
    u16*   x16c  = Gb;                      // 3.3MB in dead 8MB Gb
    u16*   W16abc = mMb;                    // 1.6MB concat in dead 4MB mMb

    auto cgrid = [](long n) { return dim3((unsigned)((n + 255) / 256)); };

    Ptr6 pBih, pBhh, pWhh;
    for (int l = 0; l < 6; ++l) { pBih.p[l] = bih[l]; pBhh.p[l] = bhh[l]; pWhh.p[l] = Whh[l]; }

    // ---- prep: dtype probe, then ALL weight transforms in one launch ----
    detect_k<<<dim3(1), dim3(256), 0, stream>>>(x_text, flagB);
    {
        long nprep = 51200L * 3 + 10752 + 100 + 7 + 6 * 1024 + 262144 + 6L * 262144 + 8192;
        prep_k<<<cgrid(nprep), dim3(256), 0, stream>>>(
            flagB, W_cWh, W_cWu, W_Ws, W_out, W_v, b_out, W_sWh, W_sWu,
            Wcwh16, Wcwu16, Wws16, Wout16, WvF, boutF, WsumB, bsumAll,
            pBih, pBhh, pWhh, WFall, cnts);
    }

    if (bigws) {
        // ---- fused input casts (syn + ctx), one launch ----
        {
            long ncast = (long)NSEQ * JJ * DD + 4L * G4 * DD + (long)BT * DD;
            castAB_k<<<cgrid(ncast), dim3(256), 0, stream>>>(
                x_syn, mx16, Wih[2], mW16ab, Wih[3],
                x_text, x16c, Wih[0], W16abc, Wih[1], flagB);
        }
        // merged syn gemm (N=2048; consumes mx16/mW16ab), then merged ctx
        // gemm (output reuses that region)
        gemm_bt<<<dim3(16, (NSEQ * JJ) / BM), dim3(256), 0, stream>>>(
            mx16, DD, mW16ab, DD, msynW, N2, bsum[2], NSEQ * JJ, N2, DD, 1);
        gemm_bt<<<dim3(16, 32), dim3(256), 0, stream>>>(
            x16c, DD, W16abc, DD, ctxW, N2, bsum[0], BT, N2, DD, 1);
        // syn LSTM: 64 groups x 4 members, XCD-packed (G8=64, grid 256), grpBase 4
        lstm_coop<<<dim3(256), dim3(256), 0, stream>>>(
            msynW, msynW + G4, WF[2], WF[3], JJ, N2,
            Ub, H2, (u16*)nullptr, 0, (const int*)nullptr,
            0, 1, 0, hx32, cnts, 4, 32, 64);
        // ctx LSTM: 2 groups x 4 members (G8=8, grid 32), grpBase 0
        lstm_coop<<<dim3(32), dim3(256), 0, stream>>>(
            ctxW, ctxW + G4, WF[0], WF[1], TT, N2,
            Gb, G4, mMb, H2, len_ctx, 0, 0, 0, hx32, cnts, 0, 1, 8);
    } else {
        // chunked synopsis (4 chunks of 64 seqs), then context — fallback
        castbf_k<<<cgrid(G4 * DD), dim3(256), 0, stream>>>(Wih[2], 0, W16a, G4 * DD, flagB);
        castbf_k<<<cgrid(G4 * DD), dim3(256), 0, stream>>>(Wih[3], 0, W16b, G4 * DD, flagB);
        for (int c = 0; c < NSEQ / SCH; ++c) {
            long chunkElems = (long)SCH * JJ * DD;
            castbf_k<<<cgrid(chunkElems), dim3(256), 0, stream>>>(x_syn, (long)c * chunkElems, x16, chunkElems, flagB);
            gemm_bt<<<dim3(8, (SCH * JJ) / BM), dim3(256), 0, stream>>>(x16, DD, W16a, DD, bufA, G4, bsum[2], SCH * JJ, G4, DD, 1);
            gemm_bt<<<dim3(8, (SCH * JJ) / BM), dim3(256), 0, stream>>>(x16, DD, W16b, DD, bufB, G4, bsum[3], SCH * JJ, G4, DD, 1);
            lstm_coop<<<dim3(64), dim3(256), 0, stream>>>(
                bufA, bufB, WF[2], WF[3], JJ, G4,
                Ub, H2, (u16*)nullptr, 0, (const int*)nullptr,
                0, 1, c * SCH, hx32, cnts, 4 + c * 16, 8, 16);
        }
        castbf_k<<<cgrid((long)BT * DD), dim3(256), 0, stream>>>(x_text, 0, x16, (long)BT * DD, flagB);
        castbf_k<<<cgrid(G4 * DD), dim3(256), 0, stream>>>(Wih[0], 0, W16a, G4 * DD, flagB);
        castbf_k<<<cgrid(G4 * DD), dim3(256), 0, stream>>>(Wih[1], 0, W16b, G4 * DD, flagB);
        gemm_bt<<<dim3(8, 32), dim3(256), 0, stream>>>(x16, DD, W16a, DD, bufA, G4, bsum[0], BT, G4, DD, 1);
        gemm_bt<<<dim3(8, 32), dim3(256), 0, stream>>>(x16, DD, W16b, DD, bufB, G4, bsum[1], BT, G4, DD, 1);
        lstm_coop<<<dim3(32), dim3(256), 0, stream>>>(
            bufA, bufB, WF[0], WF[1], TT, G4,
            Gb, G4, mMb, H2, len_ctx, 0, 0, 0, hx32, cnts, 0, 1, 8);
    }

    // ---- phase C: attention ----
    gemm_bt<<<dim3(1, 32), dim3(256), 0, stream>>>(Gb, G4, Wcwh16, H2, cWhB, MDU_, nullptr, BT, MDU_, H2, 0);
    gemm_bt<<<dim3(1, 2),  dim3(256), 0, stream>>>(Ub, H2, Wcwu16, H2, cWuB, MDU_, nullptr, NSEQ, MDU_, H2, 0);
    hprev_k<<<cgrid(BT * H2), dim3(256), 0, stream>>>(Gb, HprevB);
    gemm_bt<<<dim3(4, 32), dim3(256), 0, stream>>>(HprevB, H2, WsumB, H2, eBuf, H2, nullptr, BT, H2, H2, 0);
    s_k<<<cgrid(BT * H2), dim3(256), 0, stream>>>(eBuf, mMb, sBuf);
    gemm_bt<<<dim3(1, 32), dim3(256), 0, stream>>>(sBuf, H2, Wws16, H2, sWB, MDU_, nullptr, BT, MDU_, H2, 0);
    zz_k<<<cgrid((long)BT * SS + BT), dim3(256), 0, stream>>>(cWhB, cWuB, sWB, WvF, zB, zhatB);
    attn_mix_k<<<dim3(BT), dim3(64), 0, stream>>>(zB, zhatB, Ub, sBuf, Gb);

    // ---- phase D: layer-2 LSTM over G -> M (into mMb), groups 2,3 ----
    cast3_k<<<cgrid(2L * G4 * G4), dim3(256), 0, stream>>>(
        Wih[4], W16aD, (long)G4 * G4, Wih[5], W16aD + (size_t)G4 * G4, (long)G4 * G4,
        nullptr, nullptr, 0, flagB);
    gemm_bt<<<dim3(16, 32), dim3(256), 0, stream>>>(
        Gb, G4, W16aD, G4, mxW, N2, bsum[4], BT, N2, G4, 1);
    lstm_coop<<<dim3(32), dim3(256), 0, stream>>>(
        mxW, mxW + G4, WF[4], WF[5], TT, N2,
        mMb, H2, (u16*)nullptr, 0, (const int*)nullptr, 1, 0, 0, hx32, cnts, 2, 1, 8);

    // ---- output ----
    logit_k<<<dim3(BT / 4), dim3(256), 0, stream>>>(Gb, mMb, Wout16, boutF, d_out, flagB);
}